// Round 7
// baseline (473.245 us; speedup 1.0000x reference)
//
#include <hip/hip_runtime.h>

#define MEM_SIZE 1000000
#define DIM 128
#define BS 256
#define K 1024
#define NSC (K + 1)     // 1025 scores per (modality, batch)
#define OVFCAP 32768

constexpr float INV_TEMP = 1.0f / 0.07f;
constexpr float MOM = 0.5f;

#define NB 2048
#define BT 256
#define NWAVES (NB * BT / 64)        // 8192

typedef float fx4 __attribute__((ext_vector_type(4)));

// d_ws layout (bytes)
#define QTAB_OFF 0                   // float[512*128]   256 KB
#define CNT_OFF  262144              // int[1M]          4 MB   (build only)
#define SLOT_OFF 4456448             // int2[1M]         8 MB   (sentinel -1)
#define OVFC_OFF 12845056            // int (+pad)
#define OVF_OFF  12845312            // int2[OVFCAP]     256 KB
#define WS_NEED  13107456

__device__ __forceinline__ float wave_reduce_sum(float v) {
    #pragma unroll
    for (int off = 32; off > 0; off >>= 1)
        v += __shfl_xor(v, off, 64);
    return v;
}

// ---- setup: qtab (normalized queries) + counts=0 + slots=-1 + ovf_cnt=0 ----
__global__ __launch_bounds__(BT) void setup_kernel(
    const float* __restrict__ video, const float* __restrict__ audio,
    float* __restrict__ qtab, int* __restrict__ counts,
    int* __restrict__ slots_i, int* __restrict__ ovf_cnt) {
    const int bid = blockIdx.x;
    const int t = threadIdx.x;
    const int tid = bid * BT + t;
    if (bid < 128) {                  // 128 blocks x 4 waves = 512 units
        const int u = bid * 4 + (t >> 6);
        const int lane = t & 63;
        const int b = u & (BS - 1);
        const float* src = (u < BS) ? video : audio;
        const float2 e = reinterpret_cast<const float2*>(src + b * DIM)[lane];
        const float ss = wave_reduce_sum(e.x * e.x + e.y * e.y);
        const float inv = 1.0f / fmaxf(sqrtf(ss), 1e-12f);
        reinterpret_cast<float2*>(qtab + u * DIM)[lane] =
            make_float2(e.x * inv, e.y * inv);
    }
    for (int i = tid; i < MEM_SIZE; i += NB * BT) counts[i] = 0;
    for (int i = tid; i < 2 * MEM_SIZE; i += NB * BT) slots_i[i] = -1;
    if (tid == 0) *ovf_cnt = 0;
}

// ---- build inverted index: draw (b,j) -> row; key=(b<<11)|j ----
// E < 262144: negatives (j=jj+1); E >= 262144: positives (j=0, row=y[b]).
__global__ void build_kernel(const int* __restrict__ y,
                             const int* __restrict__ neg,
                             int* __restrict__ counts,
                             int* __restrict__ slots_i,
                             int* __restrict__ ovf_cnt,
                             int2* __restrict__ ovf) {
    const int E = blockIdx.x * blockDim.x + threadIdx.x;   // 0..262399
    int b, j, row;
    if (E < BS * K) {
        b = E >> 10;
        const int jj = E & 1023;
        j = jj + 1;
        const int ni = neg[b * K + jj];
        const int yb = y[b];
        row = ni + (ni >= yb ? 1 : 0);
    } else {
        b = E - BS * K;
        if (b >= BS) return;
        j = 0;
        row = y[b];
    }
    const int key = (b << 11) | j;
    const int old = atomicAdd(&counts[row], 1);
    if (old < 2) {
        slots_i[row * 2 + old] = key;
    } else {
        const int p = atomicAdd(ovf_cnt, 1);
        if (p < OVFCAP) ovf[p] = make_int2(row, key);
    }
}

// ---- main: nontemporal streaming copy of both banks + in-register dots ----
// Wave covers 64 fx4 = 2 rows/iter; lanes 0-31 hold row r, 32-63 hold r+1.
// slots[row] (int2, sentinel -1) is the ONLY index load — issued independently
// alongside the bank loads. For each draw: dot view2-row with qtab[b] (m=0)
// and view1-row with qtab[256+b] (m=1) using data already in registers.
__global__ __launch_bounds__(BT) void main_kernel(
    const float* __restrict__ view1, const float* __restrict__ view2,
    const float* __restrict__ qtab, const int2* __restrict__ slots,
    float* __restrict__ scores,
    fx4* __restrict__ out1, fx4* __restrict__ out2) {
    const int tid = blockIdx.x * BT + threadIdx.x;
    const int wid = tid >> 6;
    const int lane = tid & 63;
    const int half = lane >> 5;
    const int hl = lane & 31;
    const fx4* s1 = reinterpret_cast<const fx4*>(view1);
    const fx4* s2 = reinterpret_cast<const fx4*>(view2);
    const fx4* qt4 = reinterpret_cast<const fx4*>(qtab);

    const long long n4 = (long long)MEM_SIZE * DIM / 4;    // 32,000,000
    for (long long wbase = (long long)wid * 64; wbase < n4;
         wbase += (long long)NWAVES * 64) {
        const long long i = wbase + lane;
        const fx4 a = __builtin_nontemporal_load(&s1[i]);  // bank1 (view1)
        const fx4 c = __builtin_nontemporal_load(&s2[i]);  // bank2 (view2)
        const int row = (int)(wbase >> 5) + half;
        const int2 sl = slots[row];                        // broadcast, L2-hot
        __builtin_nontemporal_store(a, &out1[i]);
        __builtin_nontemporal_store(c, &out2[i]);

        #pragma unroll
        for (int t = 0; t < 2; ++t) {
            const int key = (t == 0) ? sl.x : sl.y;
            if (!__any(key >= 0)) break;                   // wave-uniform skip
            if (key >= 0) {                                // half-uniform mask
                const int b = key >> 11;
                const int j = key & 2047;
                const fx4 q0 = qt4[b * 32 + hl];           // m=0 query (video)
                const fx4 q1 = qt4[(256 + b) * 32 + hl];   // m=1 query (audio)
                float d0 = q0.x * c.x + q0.y * c.y + q0.z * c.z + q0.w * c.w;
                float d1 = q1.x * a.x + q1.y * a.y + q1.z * a.z + q1.w * a.w;
                #pragma unroll
                for (int off = 16; off > 0; off >>= 1) {   // in-half reduce
                    d0 += __shfl_xor(d0, off, 64);
                    d1 += __shfl_xor(d1, off, 64);
                }
                if (hl == 0) {
                    scores[b * NSC + j] = d0 * INV_TEMP;
                    scores[(256 + b) * NSC + j] = d1 * INV_TEMP;
                }
            }
        }
    }
}

// ---- tail: scatter (blocks 0..511) + overflow sweep (blocks 512..639) ----
__global__ void tail_kernel(const float* __restrict__ video,
                            const float* __restrict__ audio,
                            const int* __restrict__ y,
                            const float* __restrict__ view1,
                            const float* __restrict__ view2,
                            const float* __restrict__ qtab,
                            const int* __restrict__ ovf_cnt,
                            const int2* __restrict__ ovf,
                            float* __restrict__ scores,
                            float* __restrict__ out1,
                            float* __restrict__ out2) {
    const int blk = blockIdx.x;
    const int lane = threadIdx.x;
    if (blk < 512) {
        // momentum scatter; duplicate y: last write wins
        const int bank = blk >> 8;
        const int b = blk & (BS - 1);
        const int row = y[b];
        for (int b2 = b + 1; b2 < BS; ++b2)
            if (y[b2] == row) return;
        const float* emb = (bank == 0) ? video : audio;
        const float2 e = reinterpret_cast<const float2*>(emb + b * DIM)[lane];
        const float ss = wave_reduce_sum(e.x * e.x + e.y * e.y);
        const float inv = 1.0f / fmaxf(sqrtf(ss), 1e-12f);
        const float* mem = (bank == 0) ? view1 : view2;
        const float2 xp =
            reinterpret_cast<const float2*>(mem + (size_t)row * DIM)[lane];
        float2 nv = make_float2(MOM * xp.x + (1.0f - MOM) * e.x * inv,
                                MOM * xp.y + (1.0f - MOM) * e.y * inv);
        const float ss2 = wave_reduce_sum(nv.x * nv.x + nv.y * nv.y);
        const float inv2 = 1.0f / fmaxf(sqrtf(ss2), 1e-12f);
        float* out = (bank == 0) ? out1 : out2;
        reinterpret_cast<float2*>(out + (size_t)row * DIM)[lane] =
            make_float2(nv.x * inv2, nv.y * inv2);
    } else {
        // overflow entries: classic wave gather, both modalities per draw
        int n = *ovf_cnt;
        if (n > OVFCAP) n = OVFCAP;
        const float2* m1 = reinterpret_cast<const float2*>(view1);
        const float2* m2 = reinterpret_cast<const float2*>(view2);
        const float2* qt2 = reinterpret_cast<const float2*>(qtab);
        for (int e = blk - 512; e < n; e += 128) {
            const int2 rk = ovf[e];
            const int row = rk.x, key = rk.y;
            const int b = key >> 11, j = key & 2047;
            const float2 xa = m1[(size_t)row * 64 + lane];
            const float2 xc = m2[(size_t)row * 64 + lane];
            const float2 q0 = qt2[(size_t)b * 64 + lane];
            const float2 q1 = qt2[(size_t)(256 + b) * 64 + lane];
            float d0 = xc.x * q0.x + xc.y * q0.y;
            float d1 = xa.x * q1.x + xa.y * q1.y;
            #pragma unroll
            for (int off = 32; off > 0; off >>= 1) {
                d0 += __shfl_xor(d0, off, 64);
                d1 += __shfl_xor(d1, off, 64);
            }
            if (lane == 0) {
                scores[b * NSC + j] = d0 * INV_TEMP;
                scores[(256 + b) * NSC + j] = d1 * INV_TEMP;
            }
        }
    }
}

// ================= fallback (ws too small): R3 fused + scatter =============
__global__ __launch_bounds__(256) void fb_fused(
    const float* __restrict__ video, const float* __restrict__ audio,
    const int* __restrict__ y, const int* __restrict__ neg,
    const float* __restrict__ view1, const float* __restrict__ view2,
    float* __restrict__ scores,
    fx4* __restrict__ out1, fx4* __restrict__ out2) {
    const int bid = blockIdx.x;
    const int tid = threadIdx.x;
    if ((bid & 3) == 0) {
        const int bm = bid >> 2;
        const int m = bm >> 8;
        const int b = bm & (BS - 1);
        const int lane = tid & 63;
        const int wv = tid >> 6;
        const int yb = y[b];
        const float* emb = (m == 0) ? video : audio;
        const float2 e = reinterpret_cast<const float2*>(emb + b * DIM)[lane];
        const float ss = wave_reduce_sum(e.x * e.x + e.y * e.y);
        const float inv = 1.0f / fmaxf(sqrtf(ss), 1e-12f);
        const float vx = e.x * inv, vy = e.y * inv;
        const float2* mem2 =
            reinterpret_cast<const float2*>((m == 0) ? view2 : view1);
        float* srow = scores + (size_t)bm * NSC;
        const int* nb = neg + b * K;
        const int chunk = (NSC + 3) / 4;
        const int j0 = wv * chunk;
        const int j1 = min(NSC, j0 + chunk);
        for (int j = j0; j < j1; ++j) {
            int r0;
            if (j == 0) r0 = yb;
            else { const int ni = nb[j - 1]; r0 = ni + (ni >= yb ? 1 : 0); }
            const float2 x0 = mem2[(size_t)r0 * 64 + lane];
            const float s0 = wave_reduce_sum(x0.x * vx + x0.y * vy);
            if (lane == 0) srow[j] = s0 * INV_TEMP;
        }
    } else {
        const long long n4 = (long long)MEM_SIZE * DIM / 4;
        const int cb = bid - (bid >> 2) - 1;
        const fx4* s1 = reinterpret_cast<const fx4*>(view1);
        const fx4* s2 = reinterpret_cast<const fx4*>(view2);
        long long i = (long long)cb * blockDim.x + tid;
        const long long stride = (long long)1536 * blockDim.x;
        for (; i < n4; i += stride) {
            const fx4 a = __builtin_nontemporal_load(&s1[i]);
            const fx4 c = __builtin_nontemporal_load(&s2[i]);
            __builtin_nontemporal_store(a, &out1[i]);
            __builtin_nontemporal_store(c, &out2[i]);
        }
    }
}

__global__ void fb_scatter(const float* __restrict__ video,
                           const float* __restrict__ audio,
                           const int* __restrict__ y,
                           const float* __restrict__ view1,
                           const float* __restrict__ view2,
                           float* __restrict__ out1,
                           float* __restrict__ out2) {
    const int blk = blockIdx.x;
    const int lane = threadIdx.x;
    const int bank = blk >> 8;
    const int b = blk & (BS - 1);
    const int row = y[b];
    for (int b2 = b + 1; b2 < BS; ++b2)
        if (y[b2] == row) return;
    const float* emb = (bank == 0) ? video : audio;
    const float2 e = reinterpret_cast<const float2*>(emb + b * DIM)[lane];
    const float ss = wave_reduce_sum(e.x * e.x + e.y * e.y);
    const float inv = 1.0f / fmaxf(sqrtf(ss), 1e-12f);
    const float* mem = (bank == 0) ? view1 : view2;
    const float2 xp =
        reinterpret_cast<const float2*>(mem + (size_t)row * DIM)[lane];
    float2 nv = make_float2(MOM * xp.x + (1.0f - MOM) * e.x * inv,
                            MOM * xp.y + (1.0f - MOM) * e.y * inv);
    const float ss2 = wave_reduce_sum(nv.x * nv.x + nv.y * nv.y);
    const float inv2 = 1.0f / fmaxf(sqrtf(ss2), 1e-12f);
    float* out = (bank == 0) ? out1 : out2;
    reinterpret_cast<float2*>(out + (size_t)row * DIM)[lane] =
        make_float2(nv.x * inv2, nv.y * inv2);
}

extern "C" void kernel_launch(void* const* d_in, const int* in_sizes, int n_in,
                              void* d_out, int out_size, void* d_ws, size_t ws_size,
                              hipStream_t stream) {
    const float* video = (const float*)d_in[0];
    const float* audio = (const float*)d_in[1];
    const int* y       = (const int*)d_in[2];
    const int* neg     = (const int*)d_in[3];
    const float* v1    = (const float*)d_in[4];
    const float* v2    = (const float*)d_in[5];

    float* out    = (float*)d_out;
    float* scores = out;                                   // [2,256,1025]
    float* out1   = out + 2 * BS * NSC;                    // +524800 (16B-aligned)
    float* out2   = out1 + (size_t)MEM_SIZE * DIM;

    if (ws_size < (size_t)WS_NEED) {
        fb_fused<<<2048, 256, 0, stream>>>(video, audio, y, neg, v1, v2,
                                           scores, (fx4*)out1, (fx4*)out2);
        fb_scatter<<<512, 64, 0, stream>>>(video, audio, y, v1, v2, out1, out2);
        return;
    }

    char* ws = (char*)d_ws;
    float* qtab  = (float*)(ws + QTAB_OFF);
    int* counts  = (int*)(ws + CNT_OFF);
    int* slots_i = (int*)(ws + SLOT_OFF);
    int2* slots  = (int2*)(ws + SLOT_OFF);
    int* ovf_cnt = (int*)(ws + OVFC_OFF);
    int2* ovf    = (int2*)(ws + OVF_OFF);

    setup_kernel<<<NB, BT, 0, stream>>>(video, audio, qtab, counts,
                                        slots_i, ovf_cnt);
    build_kernel<<<1025, 256, 0, stream>>>(y, neg, counts, slots_i,
                                           ovf_cnt, ovf);
    main_kernel<<<NB, BT, 0, stream>>>(v1, v2, qtab, slots,
                                       scores, (fx4*)out1, (fx4*)out2);
    tail_kernel<<<640, 64, 0, stream>>>(video, audio, y, v1, v2, qtab,
                                        ovf_cnt, ovf, scores, out1, out2);
}

// Round 8
// 468.747 us; speedup vs baseline: 1.0096x; 1.0096x over previous
//
#include <hip/hip_runtime.h>

#define MEM_SIZE 1000000
#define DIM 128
#define BS 256
#define K 1024
#define NSC (K + 1)     // 1025 scores per (modality, batch)
#define OVFCAP 32768

constexpr float INV_TEMP = 1.0f / 0.07f;
constexpr float MOM = 0.5f;

#define NB 2048
#define BT 128
#define NWAVES (NB * BT / 64)        // 4096

typedef float fx4 __attribute__((ext_vector_type(4)));

// d_ws layout (bytes)
#define QTAB_OFF 0                   // float[512*128]   256 KB
#define CNT_OFF  262144              // int[1M]          4 MB   (build only)
#define SLOT_OFF 4456448             // int2[1M]         8 MB   (sentinel -1)
#define OVFC_OFF 12845056            // int (+pad)
#define OVF_OFF  12845312            // int2[OVFCAP]     256 KB
#define WS_NEED  13107456

__device__ __forceinline__ float wave_reduce_sum(float v) {
    #pragma unroll
    for (int off = 32; off > 0; off >>= 1)
        v += __shfl_xor(v, off, 64);
    return v;
}

// ---- setup: qtab (normalized queries) + counts=0 + slots=-1 + ovf_cnt=0 ----
__global__ __launch_bounds__(BT) void setup_kernel(
    const float* __restrict__ video, const float* __restrict__ audio,
    float* __restrict__ qtab, int* __restrict__ counts,
    int* __restrict__ slots_i, int* __restrict__ ovf_cnt) {
    const int bid = blockIdx.x;
    const int t = threadIdx.x;
    const int tid = bid * BT + t;
    if (bid < 256) {                  // 256 blocks x 2 waves = 512 units
        const int u = bid * 2 + (t >> 6);
        const int lane = t & 63;
        const int b = u & (BS - 1);
        const float* src = (u < BS) ? video : audio;
        const float2 e = reinterpret_cast<const float2*>(src + b * DIM)[lane];
        const float ss = wave_reduce_sum(e.x * e.x + e.y * e.y);
        const float inv = 1.0f / fmaxf(sqrtf(ss), 1e-12f);
        reinterpret_cast<float2*>(qtab + u * DIM)[lane] =
            make_float2(e.x * inv, e.y * inv);
    }
    for (int i = tid; i < MEM_SIZE; i += NB * BT) counts[i] = 0;
    for (int i = tid; i < 2 * MEM_SIZE; i += NB * BT) slots_i[i] = -1;
    if (tid == 0) *ovf_cnt = 0;
}

// ---- build inverted index: draw (b,j) -> row; key=(b<<11)|j ----
// E < 262144: negatives (j=jj+1); E >= 262144: positives (j=0, row=y[b]).
__global__ void build_kernel(const int* __restrict__ y,
                             const int* __restrict__ neg,
                             int* __restrict__ counts,
                             int* __restrict__ slots_i,
                             int* __restrict__ ovf_cnt,
                             int2* __restrict__ ovf) {
    const int E = blockIdx.x * blockDim.x + threadIdx.x;   // 0..262399
    int b, j, row;
    if (E < BS * K) {
        b = E >> 10;
        const int jj = E & 1023;
        j = jj + 1;
        const int ni = neg[b * K + jj];
        const int yb = y[b];
        row = ni + (ni >= yb ? 1 : 0);
    } else {
        b = E - BS * K;
        if (b >= BS) return;
        j = 0;
        row = y[b];
    }
    const int key = (b << 11) | j;
    const int old = atomicAdd(&counts[row], 1);
    if (old < 2) {
        slots_i[row * 2 + old] = key;
    } else {
        const int p = atomicAdd(ovf_cnt, 1);
        if (p < OVFCAP) ovf[p] = make_int2(row, key);
    }
}

// ---- main: R4-geometry streaming copy + in-register index dots ----
// 2048 blocks x 128 thr (16 waves/CU). Wave covers 64 fx4 = 2 rows/iter;
// lanes 0-31 hold row r (fx4 each), lanes 32-63 row r+1. slots[row] (int2,
// sentinel -1) is the only index load, issued alongside the bank loads.
// Slot hit: dot view2-row with qtab[b] (m=0) and view1-row with qtab[256+b]
// (m=1) on data already in registers; 5-level in-half reduce.
__global__ __launch_bounds__(BT, 4) void main_kernel(
    const float* __restrict__ view1, const float* __restrict__ view2,
    const float* __restrict__ qtab, const int2* __restrict__ slots,
    float* __restrict__ scores,
    fx4* __restrict__ out1, fx4* __restrict__ out2) {
    const int tid = blockIdx.x * BT + threadIdx.x;
    const int wid = tid >> 6;
    const int lane = tid & 63;
    const int half = lane >> 5;
    const int hl = lane & 31;
    const fx4* s1 = reinterpret_cast<const fx4*>(view1);
    const fx4* s2 = reinterpret_cast<const fx4*>(view2);
    const fx4* qt4 = reinterpret_cast<const fx4*>(qtab);

    const long long n4 = (long long)MEM_SIZE * DIM / 4;    // 32,000,000
    for (long long wbase = (long long)wid * 64; wbase < n4;
         wbase += (long long)NWAVES * 64) {
        const long long i = wbase + lane;
        const fx4 a = s1[i];                               // bank1 (view1)
        const fx4 c = s2[i];                               // bank2 (view2)
        const int row = (int)(wbase >> 5) + half;
        const int2 sl = slots[row];                        // independent 8B load
        __builtin_nontemporal_store(a, &out1[i]);
        __builtin_nontemporal_store(c, &out2[i]);

        if (__any(sl.x >= 0)) {                            // 59% skip
            #pragma unroll
            for (int t = 0; t < 2; ++t) {
                const int key = (t == 0) ? sl.x : sl.y;
                if (key >= 0) {                            // half-uniform mask
                    const int b = key >> 11;
                    const int j = key & 2047;
                    const fx4 q0 = qt4[b * 32 + hl];       // m=0 query (video)
                    const fx4 q1 = qt4[(256 + b) * 32 + hl]; // m=1 query (audio)
                    float d0 = q0.x * c.x + q0.y * c.y + q0.z * c.z + q0.w * c.w;
                    float d1 = q1.x * a.x + q1.y * a.y + q1.z * a.z + q1.w * a.w;
                    #pragma unroll
                    for (int off = 16; off > 0; off >>= 1) {  // in-half reduce
                        d0 += __shfl_xor(d0, off, 64);
                        d1 += __shfl_xor(d1, off, 64);
                    }
                    if (hl == 0) {
                        scores[b * NSC + j] = d0 * INV_TEMP;
                        scores[(256 + b) * NSC + j] = d1 * INV_TEMP;
                    }
                }
            }
        }
    }
}

// ---- tail: scatter (blocks 0..511) + overflow sweep (blocks 512..639) ----
__global__ void tail_kernel(const float* __restrict__ video,
                            const float* __restrict__ audio,
                            const int* __restrict__ y,
                            const float* __restrict__ view1,
                            const float* __restrict__ view2,
                            const float* __restrict__ qtab,
                            const int* __restrict__ ovf_cnt,
                            const int2* __restrict__ ovf,
                            float* __restrict__ scores,
                            float* __restrict__ out1,
                            float* __restrict__ out2) {
    const int blk = blockIdx.x;
    const int lane = threadIdx.x;
    if (blk < 512) {
        // momentum scatter; duplicate y: last write wins
        const int bank = blk >> 8;
        const int b = blk & (BS - 1);
        const int row = y[b];
        for (int b2 = b + 1; b2 < BS; ++b2)
            if (y[b2] == row) return;
        const float* emb = (bank == 0) ? video : audio;
        const float2 e = reinterpret_cast<const float2*>(emb + b * DIM)[lane];
        const float ss = wave_reduce_sum(e.x * e.x + e.y * e.y);
        const float inv = 1.0f / fmaxf(sqrtf(ss), 1e-12f);
        const float* mem = (bank == 0) ? view1 : view2;
        const float2 xp =
            reinterpret_cast<const float2*>(mem + (size_t)row * DIM)[lane];
        float2 nv = make_float2(MOM * xp.x + (1.0f - MOM) * e.x * inv,
                                MOM * xp.y + (1.0f - MOM) * e.y * inv);
        const float ss2 = wave_reduce_sum(nv.x * nv.x + nv.y * nv.y);
        const float inv2 = 1.0f / fmaxf(sqrtf(ss2), 1e-12f);
        float* out = (bank == 0) ? out1 : out2;
        reinterpret_cast<float2*>(out + (size_t)row * DIM)[lane] =
            make_float2(nv.x * inv2, nv.y * inv2);
    } else {
        // overflow entries: classic wave gather, both modalities per draw
        int n = *ovf_cnt;
        if (n > OVFCAP) n = OVFCAP;
        const float2* m1 = reinterpret_cast<const float2*>(view1);
        const float2* m2 = reinterpret_cast<const float2*>(view2);
        const float2* qt2 = reinterpret_cast<const float2*>(qtab);
        for (int e = blk - 512; e < n; e += 128) {
            const int2 rk = ovf[e];
            const int row = rk.x, key = rk.y;
            const int b = key >> 11, j = key & 2047;
            const float2 xa = m1[(size_t)row * 64 + lane];
            const float2 xc = m2[(size_t)row * 64 + lane];
            const float2 q0 = qt2[(size_t)b * 64 + lane];
            const float2 q1 = qt2[(size_t)(256 + b) * 64 + lane];
            float d0 = xc.x * q0.x + xc.y * q0.y;
            float d1 = xa.x * q1.x + xa.y * q1.y;
            #pragma unroll
            for (int off = 32; off > 0; off >>= 1) {
                d0 += __shfl_xor(d0, off, 64);
                d1 += __shfl_xor(d1, off, 64);
            }
            if (lane == 0) {
                scores[b * NSC + j] = d0 * INV_TEMP;
                scores[(256 + b) * NSC + j] = d1 * INV_TEMP;
            }
        }
    }
}

// ================= fallback (ws too small): R3 fused + scatter =============
__global__ __launch_bounds__(256) void fb_fused(
    const float* __restrict__ video, const float* __restrict__ audio,
    const int* __restrict__ y, const int* __restrict__ neg,
    const float* __restrict__ view1, const float* __restrict__ view2,
    float* __restrict__ scores,
    fx4* __restrict__ out1, fx4* __restrict__ out2) {
    const int bid = blockIdx.x;
    const int tid = threadIdx.x;
    if ((bid & 3) == 0) {
        const int bm = bid >> 2;
        const int m = bm >> 8;
        const int b = bm & (BS - 1);
        const int lane = tid & 63;
        const int wv = tid >> 6;
        const int yb = y[b];
        const float* emb = (m == 0) ? video : audio;
        const float2 e = reinterpret_cast<const float2*>(emb + b * DIM)[lane];
        const float ss = wave_reduce_sum(e.x * e.x + e.y * e.y);
        const float inv = 1.0f / fmaxf(sqrtf(ss), 1e-12f);
        const float vx = e.x * inv, vy = e.y * inv;
        const float2* mem2 =
            reinterpret_cast<const float2*>((m == 0) ? view2 : view1);
        float* srow = scores + (size_t)bm * NSC;
        const int* nb = neg + b * K;
        const int chunk = (NSC + 3) / 4;
        const int j0 = wv * chunk;
        const int j1 = min(NSC, j0 + chunk);
        for (int j = j0; j < j1; ++j) {
            int r0;
            if (j == 0) r0 = yb;
            else { const int ni = nb[j - 1]; r0 = ni + (ni >= yb ? 1 : 0); }
            const float2 x0 = mem2[(size_t)r0 * 64 + lane];
            const float s0 = wave_reduce_sum(x0.x * vx + x0.y * vy);
            if (lane == 0) srow[j] = s0 * INV_TEMP;
        }
    } else {
        const long long n4 = (long long)MEM_SIZE * DIM / 4;
        const int cb = bid - (bid >> 2) - 1;
        const fx4* s1 = reinterpret_cast<const fx4*>(view1);
        const fx4* s2 = reinterpret_cast<const fx4*>(view2);
        long long i = (long long)cb * blockDim.x + tid;
        const long long stride = (long long)1536 * blockDim.x;
        for (; i < n4; i += stride) {
            const fx4 a = __builtin_nontemporal_load(&s1[i]);
            const fx4 c = __builtin_nontemporal_load(&s2[i]);
            __builtin_nontemporal_store(a, &out1[i]);
            __builtin_nontemporal_store(c, &out2[i]);
        }
    }
}

__global__ void fb_scatter(const float* __restrict__ video,
                           const float* __restrict__ audio,
                           const int* __restrict__ y,
                           const float* __restrict__ view1,
                           const float* __restrict__ view2,
                           float* __restrict__ out1,
                           float* __restrict__ out2) {
    const int blk = blockIdx.x;
    const int lane = threadIdx.x;
    const int bank = blk >> 8;
    const int b = blk & (BS - 1);
    const int row = y[b];
    for (int b2 = b + 1; b2 < BS; ++b2)
        if (y[b2] == row) return;
    const float* emb = (bank == 0) ? video : audio;
    const float2 e = reinterpret_cast<const float2*>(emb + b * DIM)[lane];
    const float ss = wave_reduce_sum(e.x * e.x + e.y * e.y);
    const float inv = 1.0f / fmaxf(sqrtf(ss), 1e-12f);
    const float* mem = (bank == 0) ? view1 : view2;
    const float2 xp =
        reinterpret_cast<const float2*>(mem + (size_t)row * DIM)[lane];
    float2 nv = make_float2(MOM * xp.x + (1.0f - MOM) * e.x * inv,
                            MOM * xp.y + (1.0f - MOM) * e.y * inv);
    const float ss2 = wave_reduce_sum(nv.x * nv.x + nv.y * nv.y);
    const float inv2 = 1.0f / fmaxf(sqrtf(ss2), 1e-12f);
    float* out = (bank == 0) ? out1 : out2;
    reinterpret_cast<float2*>(out + (size_t)row * DIM)[lane] =
        make_float2(nv.x * inv2, nv.y * inv2);
}

extern "C" void kernel_launch(void* const* d_in, const int* in_sizes, int n_in,
                              void* d_out, int out_size, void* d_ws, size_t ws_size,
                              hipStream_t stream) {
    const float* video = (const float*)d_in[0];
    const float* audio = (const float*)d_in[1];
    const int* y       = (const int*)d_in[2];
    const int* neg     = (const int*)d_in[3];
    const float* v1    = (const float*)d_in[4];
    const float* v2    = (const float*)d_in[5];

    float* out    = (float*)d_out;
    float* scores = out;                                   // [2,256,1025]
    float* out1   = out + 2 * BS * NSC;                    // +524800 (16B-aligned)
    float* out2   = out1 + (size_t)MEM_SIZE * DIM;

    if (ws_size < (size_t)WS_NEED) {
        fb_fused<<<2048, 256, 0, stream>>>(video, audio, y, neg, v1, v2,
                                           scores, (fx4*)out1, (fx4*)out2);
        fb_scatter<<<512, 64, 0, stream>>>(video, audio, y, v1, v2, out1, out2);
        return;
    }

    char* ws = (char*)d_ws;
    float* qtab  = (float*)(ws + QTAB_OFF);
    int* counts  = (int*)(ws + CNT_OFF);
    int* slots_i = (int*)(ws + SLOT_OFF);
    int2* slots  = (int2*)(ws + SLOT_OFF);
    int* ovf_cnt = (int*)(ws + OVFC_OFF);
    int2* ovf    = (int2*)(ws + OVF_OFF);

    setup_kernel<<<NB, BT, 0, stream>>>(video, audio, qtab, counts,
                                        slots_i, ovf_cnt);
    build_kernel<<<1025, 256, 0, stream>>>(y, neg, counts, slots_i,
                                           ovf_cnt, ovf);
    main_kernel<<<NB, BT, 0, stream>>>(v1, v2, qtab, slots,
                                       scores, (fx4*)out1, (fx4*)out2);
    tail_kernel<<<640, 64, 0, stream>>>(video, audio, y, v1, v2, qtab,
                                        ovf_cnt, ovf, scores, out1, out2);
}

// Round 9
// 449.304 us; speedup vs baseline: 1.0533x; 1.0433x over previous
//
#include <hip/hip_runtime.h>

#define MEM_SIZE 1000000
#define DIM 128
#define BS 256
#define K 1024
#define NSC (K + 1)     // 1025 scores per (modality, batch)
#define OVFCAP 32768
#define SLOT_ENT 1008704   // 1M rows + prefetch pad (sentinel -1)

constexpr float INV_TEMP = 1.0f / 0.07f;
constexpr float MOM = 0.5f;

#define NB 2048
#define BT 128
#define NWAVES (NB * BT / 64)        // 4096
#define STEP ((long long)NWAVES * 64)  // 262144 fx4

typedef float fx4 __attribute__((ext_vector_type(4)));

// d_ws layout (bytes)
#define QTAB_OFF 0                   // float[512*128]       256 KB
#define SLOT_OFF 262144              // int2[SLOT_ENT]       ~7.7 MB
#define OVFC_OFF 8331776             // int (+pad)
#define OVF_OFF  8332032             // int2[OVFCAP]         256 KB
#define WS_NEED  8594176

__device__ __forceinline__ float wave_reduce_sum(float v) {
    #pragma unroll
    for (int off = 32; off > 0; off >>= 1)
        v += __shfl_xor(v, off, 64);
    return v;
}

// ---- setup: qtab (normalized queries) + slots=-1 + ovf_cnt=0 ----
__global__ __launch_bounds__(BT) void setup_kernel(
    const float* __restrict__ video, const float* __restrict__ audio,
    float* __restrict__ qtab, int* __restrict__ slots_i,
    int* __restrict__ ovf_cnt) {
    const int bid = blockIdx.x;
    const int t = threadIdx.x;
    const int tid = bid * BT + t;
    if (bid < 256) {                  // 256 blocks x 2 waves = 512 units
        const int u = bid * 2 + (t >> 6);
        const int lane = t & 63;
        const int b = u & (BS - 1);
        const float* src = (u < BS) ? video : audio;
        const float2 e = reinterpret_cast<const float2*>(src + b * DIM)[lane];
        const float ss = wave_reduce_sum(e.x * e.x + e.y * e.y);
        const float inv = 1.0f / fmaxf(sqrtf(ss), 1e-12f);
        reinterpret_cast<float2*>(qtab + u * DIM)[lane] =
            make_float2(e.x * inv, e.y * inv);
    }
    for (int i = tid; i < 2 * SLOT_ENT; i += NB * BT) slots_i[i] = -1;
    if (tid == 0) *ovf_cnt = 0;
}

// ---- build inverted index via double-CAS: draw (b,j) -> row ----
// E < 262144: negatives (j=jj+1); E >= 262144: positives (j=0, row=y[b]).
__global__ void build_kernel(const int* __restrict__ y,
                             const int* __restrict__ neg,
                             int* __restrict__ slots_i,
                             int* __restrict__ ovf_cnt,
                             int2* __restrict__ ovf) {
    const int E = blockIdx.x * blockDim.x + threadIdx.x;   // 0..262399
    int b, j, row;
    if (E < BS * K) {
        b = E >> 10;
        const int jj = E & 1023;
        j = jj + 1;
        const int ni = neg[b * K + jj];
        const int yb = y[b];
        row = ni + (ni >= yb ? 1 : 0);
    } else {
        b = E - BS * K;
        if (b >= BS) return;
        j = 0;
        row = y[b];
    }
    const int key = (b << 11) | j;
    if (atomicCAS(&slots_i[row * 2], -1, key) != -1) {
        if (atomicCAS(&slots_i[row * 2 + 1], -1, key) != -1) {
            const int p = atomicAdd(ovf_cnt, 1);
            if (p < OVFCAP) ovf[p] = make_int2(row, key);
        }
    }
}

// ---- main: streaming copy + in-register index dots, slots prefetched ----
// 2048 blocks x 128 thr. Wave covers 64 fx4 = 2 rows/iter; lanes 0-31 hold
// row r, lanes 32-63 row r+1. slots[row] for iteration k+1 is loaded during
// iteration k, so the per-iteration branch tests a REGISTER — the copy loop
// stays pipelineable. Slot hit: dot view2-row with qtab[b] (m=0) and
// view1-row with qtab[256+b] (m=1) on in-register data; 5-level half reduce.
__global__ __launch_bounds__(BT, 4) void main_kernel(
    const float* __restrict__ view1, const float* __restrict__ view2,
    const float* __restrict__ qtab, const int2* __restrict__ slots,
    float* __restrict__ scores,
    fx4* __restrict__ out1, fx4* __restrict__ out2) {
    const int tid = blockIdx.x * BT + threadIdx.x;
    const int wid = tid >> 6;
    const int lane = tid & 63;
    const int half = lane >> 5;
    const int hl = lane & 31;
    const fx4* s1 = reinterpret_cast<const fx4*>(view1);
    const fx4* s2 = reinterpret_cast<const fx4*>(view2);
    const fx4* qt4 = reinterpret_cast<const fx4*>(qtab);

    const long long n4 = (long long)MEM_SIZE * DIM / 4;    // 32,000,000
    long long wbase = (long long)wid * 64;
    int2 sl = slots[wid * 2 + half];                       // iter-0 entry
    for (; wbase < n4; wbase += STEP) {
        const long long i = wbase + lane;
        const fx4 a = s1[i];                               // bank1 (view1)
        const fx4 c = s2[i];                               // bank2 (view2)
        // prefetch next iteration's slot entry (padded array, no guard)
        const int2 sl_next = slots[(int)((wbase + STEP) >> 5) + half];
        __builtin_nontemporal_store(a, &out1[i]);
        __builtin_nontemporal_store(c, &out2[i]);

        if (__any(sl.x >= 0)) {                            // register test
            #pragma unroll
            for (int t = 0; t < 2; ++t) {
                const int key = (t == 0) ? sl.x : sl.y;
                if (key >= 0) {                            // half-uniform mask
                    const int b = key >> 11;
                    const int j = key & 2047;
                    const fx4 q0 = qt4[b * 32 + hl];       // m=0 query (video)
                    const fx4 q1 = qt4[(256 + b) * 32 + hl]; // m=1 query
                    float d0 = q0.x * c.x + q0.y * c.y + q0.z * c.z + q0.w * c.w;
                    float d1 = q1.x * a.x + q1.y * a.y + q1.z * a.z + q1.w * a.w;
                    #pragma unroll
                    for (int off = 16; off > 0; off >>= 1) {  // in-half reduce
                        d0 += __shfl_xor(d0, off, 64);
                        d1 += __shfl_xor(d1, off, 64);
                    }
                    if (hl == 0) {
                        scores[b * NSC + j] = d0 * INV_TEMP;
                        scores[(256 + b) * NSC + j] = d1 * INV_TEMP;
                    }
                }
            }
        }
        sl = sl_next;
    }
}

// ---- tail: scatter (blocks 0..511) + overflow sweep (blocks 512..1023) ----
__global__ void tail_kernel(const float* __restrict__ video,
                            const float* __restrict__ audio,
                            const int* __restrict__ y,
                            const float* __restrict__ view1,
                            const float* __restrict__ view2,
                            const float* __restrict__ qtab,
                            const int* __restrict__ ovf_cnt,
                            const int2* __restrict__ ovf,
                            float* __restrict__ scores,
                            float* __restrict__ out1,
                            float* __restrict__ out2) {
    const int blk = blockIdx.x;
    const int lane = threadIdx.x;
    if (blk < 512) {
        // momentum scatter; duplicate y: last write wins
        const int bank = blk >> 8;
        const int b = blk & (BS - 1);
        const int row = y[b];
        for (int b2 = b + 1; b2 < BS; ++b2)
            if (y[b2] == row) return;
        const float* emb = (bank == 0) ? video : audio;
        const float2 e = reinterpret_cast<const float2*>(emb + b * DIM)[lane];
        const float ss = wave_reduce_sum(e.x * e.x + e.y * e.y);
        const float inv = 1.0f / fmaxf(sqrtf(ss), 1e-12f);
        const float* mem = (bank == 0) ? view1 : view2;
        const float2 xp =
            reinterpret_cast<const float2*>(mem + (size_t)row * DIM)[lane];
        float2 nv = make_float2(MOM * xp.x + (1.0f - MOM) * e.x * inv,
                                MOM * xp.y + (1.0f - MOM) * e.y * inv);
        const float ss2 = wave_reduce_sum(nv.x * nv.x + nv.y * nv.y);
        const float inv2 = 1.0f / fmaxf(sqrtf(ss2), 1e-12f);
        float* out = (bank == 0) ? out1 : out2;
        reinterpret_cast<float2*>(out + (size_t)row * DIM)[lane] =
            make_float2(nv.x * inv2, nv.y * inv2);
    } else {
        // overflow entries: classic wave gather, both modalities per draw
        int n = *ovf_cnt;
        if (n > OVFCAP) n = OVFCAP;
        const float2* m1 = reinterpret_cast<const float2*>(view1);
        const float2* m2 = reinterpret_cast<const float2*>(view2);
        const float2* qt2 = reinterpret_cast<const float2*>(qtab);
        for (int e = blk - 512; e < n; e += 512) {
            const int2 rk = ovf[e];
            const int row = rk.x, key = rk.y;
            const int b = key >> 11, j = key & 2047;
            const float2 xa = m1[(size_t)row * 64 + lane];
            const float2 xc = m2[(size_t)row * 64 + lane];
            const float2 q0 = qt2[(size_t)b * 64 + lane];
            const float2 q1 = qt2[(size_t)(256 + b) * 64 + lane];
            float d0 = xc.x * q0.x + xc.y * q0.y;
            float d1 = xa.x * q1.x + xa.y * q1.y;
            #pragma unroll
            for (int off = 32; off > 0; off >>= 1) {
                d0 += __shfl_xor(d0, off, 64);
                d1 += __shfl_xor(d1, off, 64);
            }
            if (lane == 0) {
                scores[b * NSC + j] = d0 * INV_TEMP;
                scores[(256 + b) * NSC + j] = d1 * INV_TEMP;
            }
        }
    }
}

// ================= fallback (ws too small): R3 fused + scatter =============
__global__ __launch_bounds__(256) void fb_fused(
    const float* __restrict__ video, const float* __restrict__ audio,
    const int* __restrict__ y, const int* __restrict__ neg,
    const float* __restrict__ view1, const float* __restrict__ view2,
    float* __restrict__ scores,
    fx4* __restrict__ out1, fx4* __restrict__ out2) {
    const int bid = blockIdx.x;
    const int tid = threadIdx.x;
    if ((bid & 3) == 0) {
        const int bm = bid >> 2;
        const int m = bm >> 8;
        const int b = bm & (BS - 1);
        const int lane = tid & 63;
        const int wv = tid >> 6;
        const int yb = y[b];
        const float* emb = (m == 0) ? video : audio;
        const float2 e = reinterpret_cast<const float2*>(emb + b * DIM)[lane];
        const float ss = wave_reduce_sum(e.x * e.x + e.y * e.y);
        const float inv = 1.0f / fmaxf(sqrtf(ss), 1e-12f);
        const float vx = e.x * inv, vy = e.y * inv;
        const float2* mem2 =
            reinterpret_cast<const float2*>((m == 0) ? view2 : view1);
        float* srow = scores + (size_t)bm * NSC;
        const int* nb = neg + b * K;
        const int chunk = (NSC + 3) / 4;
        const int j0 = wv * chunk;
        const int j1 = min(NSC, j0 + chunk);
        for (int j = j0; j < j1; ++j) {
            int r0;
            if (j == 0) r0 = yb;
            else { const int ni = nb[j - 1]; r0 = ni + (ni >= yb ? 1 : 0); }
            const float2 x0 = mem2[(size_t)r0 * 64 + lane];
            const float s0 = wave_reduce_sum(x0.x * vx + x0.y * vy);
            if (lane == 0) srow[j] = s0 * INV_TEMP;
        }
    } else {
        const long long n4 = (long long)MEM_SIZE * DIM / 4;
        const int cb = bid - (bid >> 2) - 1;
        const fx4* s1 = reinterpret_cast<const fx4*>(view1);
        const fx4* s2 = reinterpret_cast<const fx4*>(view2);
        long long i = (long long)cb * blockDim.x + tid;
        const long long stride = (long long)1536 * blockDim.x;
        for (; i < n4; i += stride) {
            const fx4 a = __builtin_nontemporal_load(&s1[i]);
            const fx4 c = __builtin_nontemporal_load(&s2[i]);
            __builtin_nontemporal_store(a, &out1[i]);
            __builtin_nontemporal_store(c, &out2[i]);
        }
    }
}

__global__ void fb_scatter(const float* __restrict__ video,
                           const float* __restrict__ audio,
                           const int* __restrict__ y,
                           const float* __restrict__ view1,
                           const float* __restrict__ view2,
                           float* __restrict__ out1,
                           float* __restrict__ out2) {
    const int blk = blockIdx.x;
    const int lane = threadIdx.x;
    const int bank = blk >> 8;
    const int b = blk & (BS - 1);
    const int row = y[b];
    for (int b2 = b + 1; b2 < BS; ++b2)
        if (y[b2] == row) return;
    const float* emb = (bank == 0) ? video : audio;
    const float2 e = reinterpret_cast<const float2*>(emb + b * DIM)[lane];
    const float ss = wave_reduce_sum(e.x * e.x + e.y * e.y);
    const float inv = 1.0f / fmaxf(sqrtf(ss), 1e-12f);
    const float* mem = (bank == 0) ? view1 : view2;
    const float2 xp =
        reinterpret_cast<const float2*>(mem + (size_t)row * DIM)[lane];
    float2 nv = make_float2(MOM * xp.x + (1.0f - MOM) * e.x * inv,
                            MOM * xp.y + (1.0f - MOM) * e.y * inv);
    const float ss2 = wave_reduce_sum(nv.x * nv.x + nv.y * nv.y);
    const float inv2 = 1.0f / fmaxf(sqrtf(ss2), 1e-12f);
    float* out = (bank == 0) ? out1 : out2;
    reinterpret_cast<float2*>(out + (size_t)row * DIM)[lane] =
        make_float2(nv.x * inv2, nv.y * inv2);
}

extern "C" void kernel_launch(void* const* d_in, const int* in_sizes, int n_in,
                              void* d_out, int out_size, void* d_ws, size_t ws_size,
                              hipStream_t stream) {
    const float* video = (const float*)d_in[0];
    const float* audio = (const float*)d_in[1];
    const int* y       = (const int*)d_in[2];
    const int* neg     = (const int*)d_in[3];
    const float* v1    = (const float*)d_in[4];
    const float* v2    = (const float*)d_in[5];

    float* out    = (float*)d_out;
    float* scores = out;                                   // [2,256,1025]
    float* out1   = out + 2 * BS * NSC;                    // +524800 (16B-aligned)
    float* out2   = out1 + (size_t)MEM_SIZE * DIM;

    if (ws_size < (size_t)WS_NEED) {
        fb_fused<<<2048, 256, 0, stream>>>(video, audio, y, neg, v1, v2,
                                           scores, (fx4*)out1, (fx4*)out2);
        fb_scatter<<<512, 64, 0, stream>>>(video, audio, y, v1, v2, out1, out2);
        return;
    }

    char* ws = (char*)d_ws;
    float* qtab  = (float*)(ws + QTAB_OFF);
    int* slots_i = (int*)(ws + SLOT_OFF);
    int2* slots  = (int2*)(ws + SLOT_OFF);
    int* ovf_cnt = (int*)(ws + OVFC_OFF);
    int2* ovf    = (int2*)(ws + OVF_OFF);

    setup_kernel<<<NB, BT, 0, stream>>>(video, audio, qtab, slots_i, ovf_cnt);
    build_kernel<<<1025, 256, 0, stream>>>(y, neg, slots_i, ovf_cnt, ovf);
    main_kernel<<<NB, BT, 0, stream>>>(v1, v2, qtab, slots,
                                       scores, (fx4*)out1, (fx4*)out2);
    tail_kernel<<<1024, 64, 0, stream>>>(video, audio, y, v1, v2, qtab,
                                         ovf_cnt, ovf, scores, out1, out2);
}